// Round 1
// 124.941 us; speedup vs baseline: 1.0565x; 1.0565x over previous
//
#include <hip/hip_runtime.h>
#include <cstdint>

typedef unsigned long long ull;

#define N_BOX 8192
#define N_WORDS 128   // 8192 / 64
#define CH 512        // chunk size
#define WPC 8         // words per chunk
#define NBLK 16       // k5 blocks = chunks

// ---------------- workspace layout ----------------
// TB (distance>=2 transposed col-blocks): 53760 rows * 64 B = 3,440,640 @ 0
// TC (superdiagonal transposed blocks):   15 * 32 KB        =   491,520 @ 3,440,640
// TD (per-chunk diagonal tables):         16 * 32 KB        =   524,288 @ 3,932,160
// boxes4 : 131072 @ 4,456,448
// scores : 32768  @ 4,587,520
// rank   : 32768  @ 4,620,288
// maxc   : 4      @ 4,653,056
// ctrl   : 32 ints (flags[16], vb@16) @ 4,653,120
// keptg  : 16*8 ull @ 4,653,248
#define OFF_TB     0
#define OFF_TC     3440640
#define OFF_TD     3932160
#define OFF_BOXES  4456448
#define OFF_SCORES 4587520
#define OFF_RANK   4620288
#define OFF_MAXC   4653056
#define OFF_CTRL   4653120
#define OFF_KEPT   4653248

// TB rows for source chunk c' cover j >= CH*(c'+2): 7168-512c' rows (c'=0..13)
__device__ __forceinline__ int rows_before2(int c) {
    return 7424 * c - 256 * c * c;   // sum_{c'<c} (7168 - 512c')
}

__device__ __forceinline__ ull make_key(float s, int idx) {
    // positive floats: bit pattern is order-preserving. Reversed index in the
    // low 13 bits reproduces stable argsort(-conf): equal conf -> lower index first.
    return (((ull)__float_as_uint(s)) << 13) | (ull)(8191 - idx);
}

__device__ __forceinline__ float box_area(float4 b) {
    return __fmul_rn(__fsub_rn(b.z, b.x), __fsub_rn(b.w, b.y));
}

// exact replica of reference IoU rounding (_rn ops block FMA contraction); symmetric.
__device__ __forceinline__ bool iou_gt_half(float4 a, float aarea, float4 b, float barea) {
    float ix1 = fmaxf(a.x, b.x);
    float iy1 = fmaxf(a.y, b.y);
    float ix2 = fminf(a.z, b.z);
    float iy2 = fminf(a.w, b.w);
    float iw = fmaxf(__fsub_rn(ix2, ix1), 0.0f);
    float ih = fmaxf(__fsub_rn(iy2, iy1), 0.0f);
    float inter = __fmul_rn(iw, ih);
    float uni = __fsub_rn(__fadd_rn(aarea, barea), inter);
    float iou = __fdiv_rn(inter, fmaxf(uni, 1e-9f));
    return iou > 0.5f;
}

// K1: global conf max via int-bits atomicMax (conf>=0; 0xAA.. poison is negative
// int so no pre-init needed); each block zeroes its rank slice; block 0 zeroes
// the k5 control words (flags + vb counter) so stale/poisoned ws can't leak.
__global__ __launch_bounds__(256) void k1_max_zero(const float* __restrict__ in,
                                                   int* __restrict__ maxci,
                                                   int* __restrict__ rank,
                                                   int* __restrict__ ctrl) {
    int t = threadIdx.x;
    int i = blockIdx.x * 256 + t;
    float c = in[i * 5 + 4];
    for (int off = 32; off; off >>= 1) c = fmaxf(c, __shfl_down(c, off));
    __shared__ float wm[4];
    if ((t & 63) == 0) wm[t >> 6] = c;
    __syncthreads();
    if (t == 0) {
        float m = fmaxf(fmaxf(wm[0], wm[1]), fmaxf(wm[2], wm[3]));
        atomicMax(maxci, __float_as_int(m));
    }
    if (blockIdx.x == 0 && t < 32) ctrl[t] = 0;
    rank[i] = 0;
}

// K2: rank[i] = #{ j : key_j > key_i }  (descending sort position, stable ties)
// NOTE: must rank the DIVIDED scores — division can create ties raw conf lacks.
__global__ __launch_bounds__(256) void k2_rank(const float* __restrict__ in,
                                               const float* __restrict__ maxc_p,
                                               int* __restrict__ rank) {
    __shared__ ull keys[1024];
    int t = threadIdx.x;
    int bx = blockIdx.x;
    int it = bx & 31;       // i tile: 256 boxes
    int jt = bx >> 5;       // j tile: 1024 boxes (8 tiles)
    float maxc = *maxc_p;
    for (int r = 0; r < 4; ++r) {
        int j = jt * 1024 + r * 256 + t;
        float s = __fdiv_rn(in[j * 5 + 4], maxc);
        keys[r * 256 + t] = make_key(s, j);
    }
    __syncthreads();
    int i = it * 256 + t;
    ull ki = make_key(__fdiv_rn(in[i * 5 + 4], maxc), i);
    int cnt = 0;
    #pragma unroll 8
    for (int k = 0; k < 1024; ++k) cnt += (keys[k] > ki) ? 1 : 0;
    atomicAdd(&rank[i], cnt);
}

// K3: scatter boxes/scores into sorted order; also count valid boxes (vb) so
// k5 blocks don't each re-scan the score array.
__global__ __launch_bounds__(256) void k3_scatter(const float* __restrict__ in,
                                                  const int* __restrict__ rank,
                                                  const float* __restrict__ maxc_p,
                                                  float4* __restrict__ boxes4,
                                                  float* __restrict__ scores,
                                                  int* __restrict__ ctrl) {
    int i = blockIdx.x * 256 + threadIdx.x;
    float cx = in[i * 5 + 0];
    float cy = in[i * 5 + 1];
    float w  = in[i * 5 + 2];
    float h  = in[i * 5 + 3];
    float c  = in[i * 5 + 4];
    float maxc = *maxc_p;
    float s = __fdiv_rn(c, maxc);
    int r = rank[i];
    float4 b;
    b.x = __fsub_rn(cx, __fmul_rn(w, 0.5f));
    b.y = __fsub_rn(cy, __fmul_rn(h, 0.5f));
    b.z = __fadd_rn(cx, __fmul_rn(w, 0.5f));
    b.w = __fadd_rn(cy, __fmul_rn(h, 0.5f));
    boxes4[r] = b;
    scores[r] = s;
    ull bal = __ballot(s >= 0.5f);
    if ((threadIdx.x & 63) == 0) atomicAdd(&ctrl[16], (int)__popcll(bal));
}

// K4: build suppression bit tables.
//  bid <  1680        : TB — source chunk c, target j >= CH*(c+2), 32 j x 8 w tiles
//  1680 <= bid < 1920 : TC — source chunk c (0..14), target chunk c+1; transposed
//                       TC[c][w][jl] = word-w boxes of chunk c suppressing jl
//  bid >= 1920        : TD — diagonal, TD[c][w][jl], pre-masked to suppressors < jl
__global__ __launch_bounds__(256) void k4_build(const float4* __restrict__ boxes4,
                                                const float* __restrict__ scores,
                                                ull* __restrict__ TB,
                                                ull* __restrict__ TC,
                                                ull* __restrict__ TD) {
    __shared__ float4 sb[CH];
    __shared__ float sa[CH];
    int bid = blockIdx.x;
    int t = threadIdx.x;
    int c;
    int mode;   // 0=TB, 1=TC, 2=TD
    int j0;     // TB: global j tile start; TC/TD: local jl tile start
    if (bid >= 1920) {
        mode = 2;
        int d = bid - 1920;
        c = d >> 4;
        j0 = (d & 15) * 32;
    } else if (bid >= 1680) {
        mode = 1;
        int d = bid - 1680;
        c = d >> 4;          // 0..14
        j0 = (d & 15) * 32;
    } else {
        mode = 0;
        c = 0;
        int rem = bid;
        while (rem >= 224 - 16 * c) { rem -= 224 - 16 * c; ++c; }
        j0 = CH * (c + 2) + rem * 32;
    }
    if (scores[c * CH] < 0.5f) return;               // source chunk never a suppressor
    if (mode == 0 && scores[j0] < 0.5f) return;      // j-tile never alive (desc scores)

    for (int i = t; i < CH; i += 256) {
        float4 b = boxes4[c * CH + i];
        sb[i] = b;
        sa[i] = box_area(b);
    }
    __syncthreads();

    int w = t & 7;
    int r = t >> 3;          // 0..31 local row
    if (mode == 2) {
        int jl = j0 + r;
        float4 me = sb[jl];
        float ma = sa[jl];
        int wj = jl >> 6;
        int lim = (w < wj) ? 64 : ((w == wj) ? (jl & 63) : 0);
        ull bits = 0;
        for (int k = 0; k < lim; ++k)
            if (iou_gt_half(sb[w * 64 + k], sa[w * 64 + k], me, ma)) bits |= 1ull << k;
        TD[c * 4096 + w * 512 + jl] = bits;
    } else if (mode == 1) {
        int jl = j0 + r;
        int j = CH * (c + 1) + jl;
        float4 me = boxes4[j];
        float ma = box_area(me);
        ull bits = 0;
        for (int k = 0; k < 64; ++k)
            if (iou_gt_half(sb[w * 64 + k], sa[w * 64 + k], me, ma)) bits |= 1ull << k;
        TC[c * 4096 + w * 512 + jl] = bits;
    } else {
        int j = j0 + r;
        float4 me = boxes4[j];
        float ma = box_area(me);
        ull bits = 0;
        for (int k = 0; k < 64; ++k)
            if (iou_gt_half(sb[w * 64 + k], sa[w * 64 + k], me, ma)) bits |= 1ull << k;
        TB[(size_t)(rows_before2(c) + (j - CH * (c + 2))) * WPC + w] = bits;
    }
}

// K5: pipelined multi-block greedy NMS. Block c owns chunk c (16 blocks cover
// all 8192 rows). Inter-chunk dependency is ONLY the kept-word chain:
//   chunk c needs kept[c-1] (TC) and kept[c'<=c-2] (TB).
// Each block stages its TD/TC tables into LDS immediately (all CUs in
// parallel), applies TB rows lazily as earlier flags land (hidden in the
// shadow of the chain), then on flag[c-1]: 8-wave-parallel TC apply ->
// wave-0 scan -> publish kept[c] + flag[c]. Handoff: atomicExch(kept words)
// -> __threadfence() -> atomicExch(flag); consumer spins on atomic RMW then
// atomic-RMW-reads kept (device-scope, XCD-safe).
// Co-residency: 16 blocks x 16 waves x ~66KB LDS on an idle 256-CU chip all
// dispatch immediately (2 would fit per CU); no block waits on a
// not-yet-resident block. Plain launch kept for graph-capture safety.
__global__ __launch_bounds__(1024) void k5_nms(const float4* __restrict__ boxes4,
                                               const float* __restrict__ scores,
                                               const ull* __restrict__ TBg,
                                               const ull* __restrict__ TCg,
                                               const ull* __restrict__ TDg,
                                               ull* __restrict__ keptg,
                                               int* __restrict__ ctrl,
                                               float* __restrict__ out) {
    __shared__ ull TDs[CH * WPC];      // 32 KB: TD[c]
    __shared__ ull TCs[CH * WPC];      // 32 KB: TC[c-1]
    __shared__ ull kwsh[WPC];
    __shared__ unsigned amask[16];     // 512 alive bits for own chunk
    int c = blockIdx.x;
    int t = threadIdx.x;
    int lane = t & 63;
    int wave = t >> 6;
    int vb = ctrl[16];
    int nchv = (vb + CH - 1) / CH;

    if (c < nchv) {
        // ---- stage TD[c] (and TC[c-1]) into LDS; init alive mask ----
        {
            const ulonglong2* src = (const ulonglong2*)(TDg + (size_t)c * CH * WPC);
            ulonglong2* dst = (ulonglong2*)TDs;
            #pragma unroll
            for (int i2 = t; i2 < CH * WPC / 2; i2 += 1024) dst[i2] = src[i2];
        }
        if (c > 0) {
            const ulonglong2* src = (const ulonglong2*)(TCg + (size_t)(c - 1) * CH * WPC);
            ulonglong2* dst = (ulonglong2*)TCs;
            #pragma unroll
            for (int i2 = t; i2 < CH * WPC / 2; i2 += 1024) dst[i2] = src[i2];
        }
        if (t < 16) {
            int n = vb - (c * 16 + t) * 32;
            amask[t] = (n >= 32) ? 0xffffffffu : ((n <= 0) ? 0u : ((1u << n) - 1u));
        }
        __syncthreads();

        // ---- TB applies: kept[cp] -> own chunk, cp = 0..c-2 ----
        // Flags publish in chunk order, so early iterations return instantly
        // and the cp=c-2 apply overlaps block c-1's TC+scan.
        for (int cp = 0; cp + 2 <= c; ++cp) {
            if (wave == 0) {
                if (lane == 0) { while (atomicAdd(&ctrl[cp], 0) == 0) {} }
                __threadfence();
                if (lane < WPC)
                    kwsh[lane] = atomicAdd(&keptg[cp * WPC + lane], 0ull);
            }
            __syncthreads();
            ull anyk = kwsh[0] | kwsh[1] | kwsh[2] | kwsh[3] |
                       kwsh[4] | kwsh[5] | kwsh[6] | kwsh[7];
            if (anyk && t < CH) {
                if ((amask[t >> 5] >> (t & 31)) & 1u) {
                    const ull* row = TBg +
                        (size_t)(rows_before2(cp) + (c * CH + t - CH * (cp + 2))) * WPC;
                    ull a = 0;
                    #pragma unroll
                    for (int q = 0; q < WPC; ++q) a |= row[q] & kwsh[q];
                    if (a) atomicAnd(&amask[t >> 5], ~(1u << (t & 31)));
                }
            }
            __syncthreads();
        }

        // ---- TC apply: kept[c-1] -> own chunk (wave v handles target word v) ----
        if (c > 0) {
            if (wave == 0) {
                if (lane == 0) { while (atomicAdd(&ctrl[c - 1], 0) == 0) {} }
                __threadfence();
                if (lane < WPC)
                    kwsh[lane] = atomicAdd(&keptg[(c - 1) * WPC + lane], 0ull);
            }
            __syncthreads();
            if (wave < WPC) {
                bool dead = false;
                #pragma unroll
                for (int w = 0; w < WPC; ++w) {
                    ull kw = kwsh[w];
                    if (kw) dead |= (TCs[w * 512 + wave * 64 + lane] & kw) != 0ull;
                }
                ull d = __ballot(dead);
                if (lane == 0 && d) {
                    amask[2 * wave]     &= ~(unsigned)d;
                    amask[2 * wave + 1] &= ~(unsigned)(d >> 32);
                }
            }
            __syncthreads();
        }

        // ---- scan own chunk (wave 0): TD fixpoint, then publish ----
        if (wave == 0) {
            ull alive[WPC];
            #pragma unroll
            for (int w = 0; w < WPC; ++w)
                alive[w] = (ull)amask[2 * w] | ((ull)amask[2 * w + 1] << 32);
            const ull* T = TDs;
            #pragma unroll
            for (int w = 0; w < WPC; ++w) {
                ull word = alive[w];
                if (!word) continue;
                ull Tc[WPC];
                #pragma unroll
                for (int j = 0; j < WPC; ++j)
                    if (j >= w) Tc[j] = T[w * 512 + j * 64 + lane];
                ull td = Tc[w];
                ull a2 = word, kept = 0;
                while (a2 & ~kept) {
                    bool al = (a2 >> lane) & 1;
                    bool kp = (kept >> lane) & 1;
                    ull nk = __ballot(al && !kp && ((td & a2) == 0));
                    ull nd = __ballot(al && !kp && ((td & kept) != 0));
                    kept |= nk;
                    a2 &= ~nd;
                }
                alive[w] = kept;
                #pragma unroll
                for (int j = 0; j < WPC; ++j) {
                    if (j <= w) continue;
                    if (!alive[j]) continue;
                    alive[j] &= ~__ballot((Tc[j] & kept) != 0);
                }
            }
            if (lane == 0) {
                #pragma unroll
                for (int w = 0; w < WPC; ++w) {
                    atomicExch(&keptg[c * WPC + w], alive[w]);
                    amask[2 * w]     = (unsigned)alive[w];
                    amask[2 * w + 1] = (unsigned)(alive[w] >> 32);
                }
            }
            __threadfence();                       // waits the wave's exchanges, then inv
            if (lane == 0) atomicExch(&ctrl[c], 1);
        }
        __syncthreads();
    } else {
        if (t < 16) amask[t] = 0u;
        __syncthreads();
    }

    // ---- epilogue: write own 512 output rows ----
    if (t < CH) {
        int j = c * CH + t;
        bool kept = (amask[t >> 5] >> (t & 31)) & 1u;
        float4 b = boxes4[j];
        float s = scores[j];
        out[j * 5 + 0] = kept ? b.x : 0.0f;
        out[j * 5 + 1] = kept ? b.y : 0.0f;
        out[j * 5 + 2] = kept ? b.z : 0.0f;
        out[j * 5 + 3] = kept ? b.w : 0.0f;
        out[j * 5 + 4] = kept ? s   : 0.0f;
    }
}

extern "C" void kernel_launch(void* const* d_in, const int* in_sizes, int n_in,
                              void* d_out, int out_size, void* d_ws, size_t ws_size,
                              hipStream_t stream) {
    const float* in = (const float*)d_in[0];
    char* ws = (char*)d_ws;
    ull* TB        = (ull*)(ws + OFF_TB);
    ull* TC        = (ull*)(ws + OFF_TC);
    ull* TD        = (ull*)(ws + OFF_TD);
    float4* boxes4 = (float4*)(ws + OFF_BOXES);
    float* scores  = (float*)(ws + OFF_SCORES);
    int* rank      = (int*)(ws + OFF_RANK);
    float* maxc    = (float*)(ws + OFF_MAXC);
    int* ctrl      = (int*)(ws + OFF_CTRL);
    ull* keptg     = (ull*)(ws + OFF_KEPT);
    float* out     = (float*)d_out;

    k1_max_zero<<<32, 256, 0, stream>>>(in, (int*)maxc, rank, ctrl);
    k2_rank<<<256, 256, 0, stream>>>(in, maxc, rank);
    k3_scatter<<<32, 256, 0, stream>>>(in, rank, maxc, boxes4, scores, ctrl);
    k4_build<<<2176, 256, 0, stream>>>(boxes4, scores, TB, TC, TD);
    k5_nms<<<NBLK, 1024, 0, stream>>>(boxes4, scores, TB, TC, TD, keptg, ctrl, out);
}